// Round 1
// baseline (171.261 us; speedup 1.0000x reference)
//
#include <hip/hip_runtime.h>
#include <hip/hip_bf16.h>
#include <cstdint>

// LSTM cell: g[g,b,n] = sum_k A[b,k] * Wcat[g,k,n],  A = [x | h]  (K = 2048)
// then i,f,o = sigmoid(g0,1,2), u = tanh(g3), c_t = i*u + f*c, h_t = o*tanh(c_t)
// Strategy: bf16 MFMA GEMM (no fp32 MFMA on CDNA4), fused elementwise epilogue.

#define B_DIM 8192
#define D_DIM 1024
#define K_DIM 2048

typedef __attribute__((ext_vector_type(8))) short bf16x8;   // 8 bf16 = 4 VGPR
typedef __attribute__((ext_vector_type(4))) float f32x4;
typedef __attribute__((ext_vector_type(4))) unsigned int u32x4;

static __device__ __forceinline__ unsigned short f2bf(float f) {
  union { float f; unsigned int u; } v; v.f = f;
  unsigned int u = v.u;
  unsigned int r = (u + 0x7FFFu + ((u >> 16) & 1u)) >> 16;  // RTN-even
  return (unsigned short)r;
}

static __device__ __forceinline__ void load16(const void* gp, void* lp) {
  __builtin_amdgcn_global_load_lds(
      (const __attribute__((address_space(1))) void*)gp,
      (__attribute__((address_space(3))) void*)lp, 16, 0, 0);
}

static __device__ __forceinline__ float sigmoid_f(float x) {
  return 1.0f / (1.0f + __expf(-x));
}
static __device__ __forceinline__ float tanh_f(float x) {
  float e = __expf(-2.0f * fabsf(x));
  float r = (1.0f - e) / (1.0f + e);
  return copysignf(r, x);
}

// ---- prep 1: pack A = [x | h] as bf16 [8192][2048] ----
__global__ __launch_bounds__(256) void pack_a_kernel(
    const float* __restrict__ x, const float* __restrict__ h,
    unsigned short* __restrict__ Apack) {
  int t = blockIdx.x * 256 + threadIdx.x;   // one 8-element chunk per thread
  size_t base = (size_t)t * 8;
  int b = (int)(base >> 11);
  int k = (int)(base & 2047);
  const float* src = (k < 1024) ? (x + (size_t)b * 1024 + k)
                                : (h + (size_t)b * 1024 + (k - 1024));
  float4 v0 = ((const float4*)src)[0];
  float4 v1 = ((const float4*)src)[1];
  union { unsigned short s[8]; u32x4 v; } o;
  o.s[0] = f2bf(v0.x); o.s[1] = f2bf(v0.y); o.s[2] = f2bf(v0.z); o.s[3] = f2bf(v0.w);
  o.s[4] = f2bf(v1.x); o.s[5] = f2bf(v1.y); o.s[6] = f2bf(v1.z); o.s[7] = f2bf(v1.w);
  *(u32x4*)(Apack + base) = o.v;
}

// ---- prep 2: Wt[g][n][k] = bf16( k<1024 ? Wx[g][k][n] : Wh[g][k-1024][n] ) ----
__global__ __launch_bounds__(256) void prep_w_kernel(
    const float* __restrict__ Wx, const float* __restrict__ Wh,
    unsigned short* __restrict__ Wt) {
  __shared__ float tile[32][33];           // +1 pad: no bank conflicts
  int bid = blockIdx.x;
  int g = bid >> 11;                       // 2048 tiles per gate
  int rem = bid & 2047;
  int kt = rem >> 5;                       // 0..63  (k tiles, span 2048)
  int nt = rem & 31;                       // 0..31  (n tiles, span 1024)
  int k0 = kt * 32, n0 = nt * 32;
  int tx = threadIdx.x & 31, ty = threadIdx.x >> 5;   // 32 x 8
  const float* Wsrc;
  int ks;
  if (k0 < 1024) { Wsrc = Wx + (size_t)g * 1048576; ks = k0; }
  else           { Wsrc = Wh + (size_t)g * 1048576; ks = k0 - 1024; }
  #pragma unroll
  for (int s = 0; s < 4; ++s) {
    int r = ty + s * 8;
    tile[r][tx] = Wsrc[(size_t)(ks + r) * 1024 + n0 + tx];  // coalesced in n
  }
  __syncthreads();
  #pragma unroll
  for (int s = 0; s < 4; ++s) {
    int r = ty + s * 8;
    // Wt[g][n0+r][k0+tx] = W[k0+tx][n0+r]
    Wt[(size_t)((g << 10) + n0 + r) * 2048 + k0 + tx] = f2bf(tile[tx][r]);
  }
}

// ---- main: fused 4-gate GEMM + LSTM epilogue ----
// Tile: BM=128, BN=32 per gate (x4 gates), BK=64. 256 threads = 4 waves,
// wave w owns rows [w*32, w*32+32). LDS 2 x (A 16KB + 4x B 4KB) = 64KB.
__global__ __launch_bounds__(256, 2) void lstm_gemm_kernel(
    const unsigned short* __restrict__ Apack,   // [8192][2048] bf16
    const unsigned short* __restrict__ Wt,      // [4][1024][2048] bf16 (B^T)
    const float* __restrict__ cprev,
    float* __restrict__ out) {
  extern __shared__ char lds[];
  const int tid = threadIdx.x;
  const int l = tid & 63;
  const int w = tid >> 6;
  const int bid = blockIdx.x;
  const int mt = bid >> 5;             // 64 m-tiles
  const int nt = bid & 31;             // 32 n-tiles
  const int m0 = mt << 7;
  const int n0 = nt << 5;

  f32x4 acc[4][2][2];
  #pragma unroll
  for (int g = 0; g < 4; ++g)
    #pragma unroll
    for (int a = 0; a < 2; ++a)
      #pragma unroll
      for (int b = 0; b < 2; ++b) acc[g][a][b] = (f32x4)0.0f;

  // Stage K-tile t into LDS buffer buf. Linear LDS dest (global_load_lds
  // requirement), inverse-XOR-swizzled GLOBAL source; reads apply same XOR.
  auto stage = [&](int buf, int t) {
    const int k0 = t << 6;
    char* base = lds + buf * 32768;
    // A tile [128 rows][64 k] bf16, row stride 128B -> 4 insts x 256 thr x 16B
    #pragma unroll
    for (int j = 0; j < 4; ++j) {
      int c = j * 256 + tid;
      int Dd = c << 4;                       // linear byte in tile
      int row = Dd >> 7;
      int kbs = (Dd & 127) ^ ((row & 7) << 4);
      const unsigned short* gp = Apack + (size_t)(m0 + row) * 2048 + k0 + (kbs >> 1);
      load16(gp, base + ((c & ~63) << 4));   // wave-uniform base + lane*16
    }
    // B tiles: 4 gates x [32 rows(n)][64 k], 4KB each
    #pragma unroll
    for (int g = 0; g < 4; ++g) {
      int Dd = tid << 4;
      int row = Dd >> 7;
      int kbs = (Dd & 127) ^ ((row & 7) << 4);
      const unsigned short* gp =
          Wt + (size_t)((g << 10) + n0 + row) * 2048 + k0 + (kbs >> 1);
      load16(gp, base + 16384 + (g << 12) + ((tid & ~63) << 4));
    }
  };

  const int lr = l & 15;
  const int kgrp = (l >> 4) << 4;            // k-group byte offset 0/16/32/48
  const int arow = w * 32 + lr;
  const int sA = (arow & 7) << 4;            // row-XOR swizzle (same for row,row+16)
  const int sB = (lr & 7) << 4;

  stage(0, 0);
  int cur = 0;
  for (int t = 0; t < 32; ++t) {
    __syncthreads();                          // drains vmcnt: buf[cur] ready
    if (t + 1 < 32) stage(cur ^ 1, t + 1);    // async prefetch overlaps compute
    const char* Ab = lds + cur * 32768;
    const char* Bb = Ab + 16384;
    #pragma unroll
    for (int ks = 0; ks < 2; ++ks) {
      const int kb = ks * 64 + kgrp;
      bf16x8 a0 = *(const bf16x8*)(Ab + arow * 128 + (kb ^ sA));
      bf16x8 a1 = *(const bf16x8*)(Ab + (arow + 16) * 128 + (kb ^ sA));
      #pragma unroll
      for (int g = 0; g < 4; ++g) {
        const char* Bg = Bb + (g << 12);
        bf16x8 b0 = *(const bf16x8*)(Bg + lr * 128 + (kb ^ sB));
        bf16x8 b1 = *(const bf16x8*)(Bg + (lr + 16) * 128 + (kb ^ sB));
        acc[g][0][0] = __builtin_amdgcn_mfma_f32_16x16x32_bf16(a0, b0, acc[g][0][0], 0, 0, 0);
        acc[g][0][1] = __builtin_amdgcn_mfma_f32_16x16x32_bf16(a0, b1, acc[g][0][1], 0, 0, 0);
        acc[g][1][0] = __builtin_amdgcn_mfma_f32_16x16x32_bf16(a1, b0, acc[g][1][0], 0, 0, 0);
        acc[g][1][1] = __builtin_amdgcn_mfma_f32_16x16x32_bf16(a1, b1, acc[g][1][1], 0, 0, 0);
      }
    }
    cur ^= 1;
  }

  // Epilogue: C/D layout col = lane&15, row = (lane>>4)*4 + reg  [m89]
  const int rbase = m0 + w * 32;
  #pragma unroll
  for (int mf = 0; mf < 2; ++mf) {
    #pragma unroll
    for (int nf = 0; nf < 2; ++nf) {
      int col = n0 + nf * 16 + lr;
      #pragma unroll
      for (int j = 0; j < 4; ++j) {
        int rrow = rbase + mf * 16 + ((l >> 4) << 2) + j;
        float gi = acc[0][mf][nf][j];
        float gf = acc[1][mf][nf][j];
        float go = acc[2][mf][nf][j];
        float gu = acc[3][mf][nf][j];
        float i_ = sigmoid_f(gi);
        float f_ = sigmoid_f(gf);
        float o_ = sigmoid_f(go);
        float u_ = tanh_f(gu);
        size_t idx = (size_t)rrow * 1024 + col;
        float ct = i_ * u_ + f_ * cprev[idx];
        float ht = o_ * tanh_f(ct);
        out[idx] = ht;                         // h_t
        out[8388608 + idx] = ct;               // c_t  (B*D offset)
      }
    }
  }
}

extern "C" void kernel_launch(void* const* d_in, const int* in_sizes, int n_in,
                              void* d_out, int out_size, void* d_ws, size_t ws_size,
                              hipStream_t stream) {
  const float* x  = (const float*)d_in[0];
  const float* h  = (const float*)d_in[1];
  const float* c  = (const float*)d_in[2];
  const float* Wx = (const float*)d_in[3];
  const float* Wh = (const float*)d_in[4];
  float* out = (float*)d_out;

  unsigned short* Apack = (unsigned short*)d_ws;                  // 33,554,432 B
  unsigned short* Wt = (unsigned short*)((char*)d_ws + 33554432); // 16,777,216 B

  pack_a_kernel<<<8192, 256, 0, stream>>>(x, h, Apack);
  prep_w_kernel<<<8192, 256, 0, stream>>>(Wx, Wh, Wt);
  lstm_gemm_kernel<<<2048, 256, 65536, stream>>>(Apack, Wt, c, out);
}